// Round 19
// baseline (13.105 us; speedup 1.0000x reference)
//
#include <hip/hip_runtime.h>

#define D_ 256
#define N_ 64
#define JT 32
#define CS 4
#define CMAX 96
#define GRID (N_ * CS * 2)  // 512 = 8 XCDs * 64 (bijective): (n, h, par)

typedef __attribute__((ext_vector_type(8))) short short8;  // bf16x8 frag
typedef __attribute__((ext_vector_type(4))) float f32x4;   // C/D frag

// R19 = R18 (11.08us, prediction-matched) with the tile loop SPLIT across
// block pairs: block = (n, h, par); par-block does tiles g = par, par+2, ...
// The 8 blocks of a position are linear-consecutive -> same XCD -> twin's
// B-chunk + V reads are L2 hits (HBM unchanged). Wins: G=2 makespan halves
// (1 block/CU -> slowest block was the kernel), and 2 blocks/CU overlap the
// scan/V RTT chains. Inner machinery identical to R18.
__global__ __launch_bounds__(512) void fused_mpt_mfma(
    const void* __restrict__ positions_raw, const float* __restrict__ outputs,
    const float* __restrict__ table, float* __restrict__ out) {
  __shared__ __align__(16) unsigned short vhi[2][JT][272];  // 34.8KB
  __shared__ int sidx[CMAX];
  __shared__ int wcnt[8];

  const int b = blockIdx.x;
  const int linear = (b & 7) * (GRID / 8) + (b >> 3);  // XCD-bijective
  const int n = linear >> 3;         // 8 consecutive linear ids share n
  const int h = (linear >> 1) & 3;   // col chunk
  const int par = linear & 1;        // tile parity

  const int t = threadIdx.x;
  const int w = t >> 6;   // 0..7
  const int l = t & 63;
  const int cg = w & 3;   // 16-col group within the 64-col chunk
  const int sh = w >> 2;  // A-row half: rows [16*sh, 16*sh+16) of the tile

  const int col = h * 64 + cg * 16 + (l & 15);
  const int kg = (l >> 4) * 8;
  const int arow = sh * 16 + (l & 15);
  const float* Mcol = table + (size_t)n * (D_ * D_) + col;

  const int* p32 = (const int*)positions_raw;
  const long long* p64 = (const long long*)positions_raw;

  // ---- scan loads FIRST (int64 = fast path; oldest in vmcnt queue) ----
  long long pq[4];
  const int idx0 = w * 256;  // wave covers pair indices [256w, 256w+256)
#pragma unroll
  for (int r = 0; r < 4; ++r) pq[r] = p64[idx0 + r * 64 + l];
  __builtin_amdgcn_sched_barrier(0);  // pin: B must not hoist above scan

  // ---- B prefetch: full K, 64 loads all in flight (twin's = L2 hits) ----
  float mb[8][8];
#pragma unroll
  for (int s = 0; s < 8; ++s) {
#pragma unroll
    for (int i = 0; i < 8; ++i)
      mb[s][i] = Mcol[(size_t)(s * 32 + kg + i) * D_];
  }
  __builtin_amdgcn_sched_barrier(0);

  // ---- layout check: int64 <=> all hi-dwords zero (values < 64) ----
  unsigned long long hi_nz = 0ull;
#pragma unroll
  for (int r = 0; r < 4; ++r) hi_nz |= __ballot((int)(pq[r] >> 32) != 0);
  int pv[4];
  if (hi_nz == 0ull) {  // int64 fast path (taken: npz stores int64)
#pragma unroll
    for (int r = 0; r < 4; ++r) pv[r] = (int)pq[r];
  } else {  // int32 layout fallback (wave-uniform)
#pragma unroll
    for (int r = 0; r < 4; ++r) pv[r] = p32[idx0 + r * 64 + l];
  }

  // ---- ballots + rank emit (B keeps flying) ----
  unsigned long long msk[4];
  int cw = 0;
#pragma unroll
  for (int r = 0; r < 4; ++r) {
    msk[r] = __ballot(pv[r] == n);
    cw += __popcll(msk[r]);
  }
  if (l == 0) wcnt[w] = cw;
  __syncthreads();
  int c = 0, base = 0;
#pragma unroll
  for (int ww = 0; ww < 8; ++ww) {
    const int cc = wcnt[ww];
    if (ww < w) base += cc;
    c += cc;
  }
  if (c > CMAX) c = CMAX;

  const int G = (c + JT - 1) >> 5;
  if (par >= G) return;  // block-uniform (covers c==0 too)

  const unsigned long long lt = (1ull << l) - 1ull;
  int run = base;
#pragma unroll
  for (int r = 0; r < 4; ++r) {
    const int g = run + __popcll(msk[r] & lt);
    if (((msk[r] >> l) & 1ull) && g < CMAX) sidx[g] = idx0 + r * 64 + l;
    run += __popcll(msk[r]);
  }
  __syncthreads();

  // ---- staging role: thread = (row, 16-wide dgroup) ----
  const int srow = t & 31;
  const int d0 = (t >> 5) * 16;

  // V tile `par`: 4 float4 loads per thread (row-contiguous, coalesced)
  float4 v0, v1, v2, v3;
  {
    const int q = par * JT + srow;
    const int idx = (q < c) ? sidx[q] : -1;
    if (idx >= 0) {
      const float* vp = &outputs[(size_t)idx * D_ + d0];
      v0 = *(const float4*)vp;
      v1 = *(const float4*)(vp + 4);
      v2 = *(const float4*)(vp + 8);
      v3 = *(const float4*)(vp + 12);
    } else {
      v0 = v1 = v2 = v3 = make_float4(0.f, 0.f, 0.f, 0.f);
    }
  }

  // ---- convert B once: split hi/lo (drains B; V stays in flight) ----
  short8 BH[8], BL[8];
#pragma unroll
  for (int s = 0; s < 8; ++s) {
    union {
      short8 v;
      unsigned u[4];
    } H, L;
#pragma unroll
    for (int p = 0; p < 4; ++p) {
      const unsigned b0 = __float_as_uint(mb[s][2 * p]);
      const unsigned b1 = __float_as_uint(mb[s][2 * p + 1]);
      H.u[p] = (b0 >> 16) | (b1 & 0xffff0000u);
      const float l0 = mb[s][2 * p] - __uint_as_float(b0 & 0xffff0000u);
      const float l1 = mb[s][2 * p + 1] - __uint_as_float(b1 & 0xffff0000u);
      L.u[p] =
          (__float_as_uint(l0) >> 16) | (__float_as_uint(l1) & 0xffff0000u);
    }
    BH[s] = H.v;
    BL[s] = L.v;
  }

  for (int g = par; g < G; g += 2) {
    const int cur = ((g - par) >> 1) & 1;

    // ---- stage V(g): truncate-pack 16 bf16, 2 ds_write_b128 ----
    {
      const float vv[16] = {v0.x, v0.y, v0.z, v0.w, v1.x, v1.y, v1.z, v1.w,
                            v2.x, v2.y, v2.z, v2.w, v3.x, v3.y, v3.z, v3.w};
      union {
        short8 v;
        unsigned u[4];
      } Ha, Hb;
#pragma unroll
      for (int p = 0; p < 4; ++p) {
        const unsigned a0 = __float_as_uint(vv[2 * p]);
        const unsigned a1 = __float_as_uint(vv[2 * p + 1]);
        Ha.u[p] = (a0 >> 16) | (a1 & 0xffff0000u);
        const unsigned b0 = __float_as_uint(vv[8 + 2 * p]);
        const unsigned b1 = __float_as_uint(vv[8 + 2 * p + 1]);
        Hb.u[p] = (b0 >> 16) | (b1 & 0xffff0000u);
      }
      *(short8*)&vhi[cur][srow][d0] = Ha.v;
      *(short8*)&vhi[cur][srow][d0 + 8] = Hb.v;
    }

    // ---- issue V(g+2) (lands under kloop; regs free after stage) ----
    if (g + 2 < G) {
      const int q = (g + 2) * JT + srow;
      const int idx = (q < c) ? sidx[q] : -1;
      if (idx >= 0) {
        const float* vp = &outputs[(size_t)idx * D_ + d0];
        v0 = *(const float4*)vp;
        v1 = *(const float4*)(vp + 4);
        v2 = *(const float4*)(vp + 8);
        v3 = *(const float4*)(vp + 12);
      } else {
        v0 = v1 = v2 = v3 = make_float4(0.f, 0.f, 0.f, 0.f);
      }
    }

    __syncthreads();  // vhi[cur] ready (also fences reuse from g-4)

    // ---- kloop(g): full K, 8 steps x 2 MFMA; acc complete ----
    f32x4 accA = {0.f, 0.f, 0.f, 0.f};
    f32x4 accB = {0.f, 0.f, 0.f, 0.f};
#pragma unroll
    for (int s = 0; s < 8; ++s) {
      const short8 ahi = *(const short8*)&vhi[cur][arow][s * 32 + kg];
      accA = __builtin_amdgcn_mfma_f32_16x16x32_bf16(ahi, BH[s], accA, 0, 0, 0);
      accB = __builtin_amdgcn_mfma_f32_16x16x32_bf16(ahi, BL[s], accB, 0, 0, 0);
    }
    const f32x4 acc = accA + accB;

    // ---- direct store: row = sh*16 + (l>>4)*4 + r (m89), col = lane col ----
#pragma unroll
    for (int r = 0; r < 4; ++r) {
      const int q = g * JT + sh * 16 + (l >> 4) * 4 + r;
      if (q < c) out[(size_t)sidx[q] * D_ + col] = acc[r];
    }
  }
}

extern "C" void kernel_launch(void* const* d_in, const int* in_sizes, int n_in,
                              void* d_out, int out_size, void* d_ws,
                              size_t ws_size, hipStream_t stream) {
  const void* positions = d_in[0];
  const float* outputs = (const float*)d_in[1];
  const float* table = (const float*)d_in[2];
  float* out = (float*)d_out;
  (void)d_ws;
  (void)ws_size;

  fused_mpt_mfma<<<GRID, 512, 0, stream>>>(positions, outputs, table, out);
}

// Round 20
// 10.839 us; speedup vs baseline: 1.2091x; 1.2091x over previous
//
#include <hip/hip_runtime.h>

#define D_ 256
#define N_ 64
#define JT 32
#define CS 4
#define CMAX 96
#define GRID (N_ * CS)  // 256 blocks = 8 XCDs * 32 (bijective), 1/CU

typedef __attribute__((ext_vector_type(8))) short short8;  // bf16x8 frag
typedef __attribute__((ext_vector_type(4))) float f32x4;   // C/D frag

// R20 = R18 verbatim (best measured: 11.08us, prediction-matched).
// R19's block-pair split (+2.0us) and R16's barrier-free variant (+2.4us)
// bracket this shape from both sides: one block/CU, one prologue per
// position-chunk, deep tile loop, LDS-staged V, full-K waves, direct store.
// Numerics (R16/R17-validated): acc = trunc_bf16(V).(Bh+Bl), absmax 0.5
// (threshold 1.62). C/D mapping m89-verified: col=l&15, row=(l>>4)*4+reg.
__global__ __launch_bounds__(512) void fused_mpt_mfma(
    const void* __restrict__ positions_raw, const float* __restrict__ outputs,
    const float* __restrict__ table, float* __restrict__ out) {
  __shared__ __align__(16) unsigned short vhi[2][JT][272];  // 34.8KB
  __shared__ int sidx[CMAX];
  __shared__ int wcnt[8];

  const int b = blockIdx.x;
  const int linear = (b & 7) * (GRID / 8) + (b >> 3);  // XCD-bijective
  const int n = linear >> 2;
  const int h = linear & 3;

  const int t = threadIdx.x;
  const int w = t >> 6;   // 0..7
  const int l = t & 63;
  const int cg = w & 3;   // 16-col group within the 64-col chunk
  const int sh = w >> 2;  // A-row half: rows [16*sh, 16*sh+16) of the tile

  const int col = h * 64 + cg * 16 + (l & 15);
  const int kg = (l >> 4) * 8;
  const int arow = sh * 16 + (l & 15);
  const float* Mcol = table + (size_t)n * (D_ * D_) + col;

  const int* p32 = (const int*)positions_raw;
  const long long* p64 = (const long long*)positions_raw;

  // ---- scan loads FIRST (int64 = fast path; oldest in vmcnt queue) ----
  long long pq[4];
  const int idx0 = w * 256;  // wave covers pair indices [256w, 256w+256)
#pragma unroll
  for (int r = 0; r < 4; ++r) pq[r] = p64[idx0 + r * 64 + l];
  __builtin_amdgcn_sched_barrier(0);  // pin: B must not hoist above scan

  // ---- B prefetch: full K, 64 loads all in flight ----
  float mb[8][8];
#pragma unroll
  for (int s = 0; s < 8; ++s) {
#pragma unroll
    for (int i = 0; i < 8; ++i)
      mb[s][i] = Mcol[(size_t)(s * 32 + kg + i) * D_];
  }
  __builtin_amdgcn_sched_barrier(0);

  // ---- layout check: int64 <=> all hi-dwords zero (values < 64) ----
  unsigned long long hi_nz = 0ull;
#pragma unroll
  for (int r = 0; r < 4; ++r) hi_nz |= __ballot((int)(pq[r] >> 32) != 0);
  int pv[4];
  if (hi_nz == 0ull) {  // int64 fast path (taken: npz stores int64)
#pragma unroll
    for (int r = 0; r < 4; ++r) pv[r] = (int)pq[r];
  } else {  // int32 layout fallback (wave-uniform)
#pragma unroll
    for (int r = 0; r < 4; ++r) pv[r] = p32[idx0 + r * 64 + l];
  }

  // ---- ballots + rank emit (B keeps flying) ----
  unsigned long long msk[4];
  int cw = 0;
#pragma unroll
  for (int r = 0; r < 4; ++r) {
    msk[r] = __ballot(pv[r] == n);
    cw += __popcll(msk[r]);
  }
  if (l == 0) wcnt[w] = cw;
  __syncthreads();
  int c = 0, base = 0;
#pragma unroll
  for (int ww = 0; ww < 8; ++ww) {
    const int cc = wcnt[ww];
    if (ww < w) base += cc;
    c += cc;
  }
  if (c > CMAX) c = CMAX;
  if (c == 0) return;  // block-uniform: position unused

  const unsigned long long lt = (1ull << l) - 1ull;
  int run = base;
#pragma unroll
  for (int r = 0; r < 4; ++r) {
    const int g = run + __popcll(msk[r] & lt);
    if (((msk[r] >> l) & 1ull) && g < CMAX) sidx[g] = idx0 + r * 64 + l;
    run += __popcll(msk[r]);
  }
  __syncthreads();

  // ---- staging role: thread = (row, 16-wide dgroup) ----
  const int srow = t & 31;
  const int d0 = (t >> 5) * 16;

  // V tile 0: 4 float4 loads per thread (row-contiguous, coalesced)
  float4 v0, v1, v2, v3;
  {
    const int idx = (srow < c) ? sidx[srow] : -1;
    if (idx >= 0) {
      const float* vp = &outputs[(size_t)idx * D_ + d0];
      v0 = *(const float4*)vp;
      v1 = *(const float4*)(vp + 4);
      v2 = *(const float4*)(vp + 8);
      v3 = *(const float4*)(vp + 12);
    } else {
      v0 = v1 = v2 = v3 = make_float4(0.f, 0.f, 0.f, 0.f);
    }
  }

  // ---- convert B once: split hi/lo (drains B; V stays in flight) ----
  short8 BH[8], BL[8];
#pragma unroll
  for (int s = 0; s < 8; ++s) {
    union {
      short8 v;
      unsigned u[4];
    } H, L;
#pragma unroll
    for (int p = 0; p < 4; ++p) {
      const unsigned b0 = __float_as_uint(mb[s][2 * p]);
      const unsigned b1 = __float_as_uint(mb[s][2 * p + 1]);
      H.u[p] = (b0 >> 16) | (b1 & 0xffff0000u);
      const float l0 = mb[s][2 * p] - __uint_as_float(b0 & 0xffff0000u);
      const float l1 = mb[s][2 * p + 1] - __uint_as_float(b1 & 0xffff0000u);
      L.u[p] =
          (__float_as_uint(l0) >> 16) | (__float_as_uint(l1) & 0xffff0000u);
    }
    BH[s] = H.v;
    BL[s] = L.v;
  }

  const int G = (c + JT - 1) >> 5;

  for (int g = 0; g < G; ++g) {
    const int cur = g & 1;

    // ---- stage V(g): truncate-pack 16 bf16, 2 ds_write_b128 ----
    {
      const float vv[16] = {v0.x, v0.y, v0.z, v0.w, v1.x, v1.y, v1.z, v1.w,
                            v2.x, v2.y, v2.z, v2.w, v3.x, v3.y, v3.z, v3.w};
      union {
        short8 v;
        unsigned u[4];
      } Ha, Hb;
#pragma unroll
      for (int p = 0; p < 4; ++p) {
        const unsigned a0 = __float_as_uint(vv[2 * p]);
        const unsigned a1 = __float_as_uint(vv[2 * p + 1]);
        Ha.u[p] = (a0 >> 16) | (a1 & 0xffff0000u);
        const unsigned b0 = __float_as_uint(vv[8 + 2 * p]);
        const unsigned b1 = __float_as_uint(vv[8 + 2 * p + 1]);
        Hb.u[p] = (b0 >> 16) | (b1 & 0xffff0000u);
      }
      *(short8*)&vhi[cur][srow][d0] = Ha.v;
      *(short8*)&vhi[cur][srow][d0 + 8] = Hb.v;
    }

    // ---- issue V(g+1) (lands under kloop; regs free after stage) ----
    if (g + 1 < G) {
      const int q = (g + 1) * JT + srow;
      const int idx = (q < c) ? sidx[q] : -1;
      if (idx >= 0) {
        const float* vp = &outputs[(size_t)idx * D_ + d0];
        v0 = *(const float4*)vp;
        v1 = *(const float4*)(vp + 4);
        v2 = *(const float4*)(vp + 8);
        v3 = *(const float4*)(vp + 12);
      } else {
        v0 = v1 = v2 = v3 = make_float4(0.f, 0.f, 0.f, 0.f);
      }
    }

    __syncthreads();  // vhi[cur] ready (also fences reuse of vhi[cur] from g-2)

    // ---- kloop(g): full K, 8 steps x 2 MFMA; acc complete ----
    f32x4 accA = {0.f, 0.f, 0.f, 0.f};
    f32x4 accB = {0.f, 0.f, 0.f, 0.f};
#pragma unroll
    for (int s = 0; s < 8; ++s) {
      const short8 ahi = *(const short8*)&vhi[cur][arow][s * 32 + kg];
      accA = __builtin_amdgcn_mfma_f32_16x16x32_bf16(ahi, BH[s], accA, 0, 0, 0);
      accB = __builtin_amdgcn_mfma_f32_16x16x32_bf16(ahi, BL[s], accB, 0, 0, 0);
    }
    const f32x4 acc = accA + accB;

    // ---- direct store: row = sh*16 + (l>>4)*4 + r (m89), col = lane col ----
#pragma unroll
    for (int r = 0; r < 4; ++r) {
      const int q = g * JT + sh * 16 + (l >> 4) * 4 + r;
      if (q < c) out[(size_t)sidx[q] * D_ + col] = acc[r];
    }
  }
}

extern "C" void kernel_launch(void* const* d_in, const int* in_sizes, int n_in,
                              void* d_out, int out_size, void* d_ws,
                              size_t ws_size, hipStream_t stream) {
  const void* positions = d_in[0];
  const float* outputs = (const float*)d_in[1];
  const float* table = (const float*)d_in[2];
  float* out = (float*)d_out;
  (void)d_ws;
  (void)ws_size;

  fused_mpt_mfma<<<GRID, 512, 0, stream>>>(positions, outputs, table, out);
}